// Round 17
// baseline (298.167 us; speedup 1.0000x reference)
//
#include <hip/hip_runtime.h>
#include <hip/hip_bf16.h>

#define BB 8
#define CIN 512
#define COUT 512
#define HH 64
#define WW 64

#define AFF_SCALE 0.044194173824159216f     // 1/sqrt(512)
#define CONV_SCALE 0.014731391274719736f    // 1/sqrt(4608)
#define CONV_SCALE2 (1.0f/4608.0f)

typedef short s16x8 __attribute__((ext_vector_type(8)));
typedef float f32x16 __attribute__((ext_vector_type(16)));

__device__ __forceinline__ unsigned short f2bf(float f) {
  __hip_bfloat16 h = __float2bfloat16(f);
  return *reinterpret_cast<unsigned short*>(&h);
}

// zero-register global->LDS DMA, 16B per lane; LDS dest = uniform base + lane*16
__device__ __forceinline__ void gload_lds16(const void* g, void* l) {
  __builtin_amdgcn_global_load_lds(
      (const __attribute__((address_space(1))) unsigned int*)g,
      (__attribute__((address_space(3))) unsigned int*)l, 16, 0, 0);
}

// ---------------------------------------------------------------------------
// prep1: fused {affine | wsq | wpack}  (independent passes, block-ranged)
// ---------------------------------------------------------------------------
__global__ __launch_bounds__(256) void prep1_kernel(
    const float* __restrict__ style, const float* __restrict__ wa,
    const float* __restrict__ ba, float* __restrict__ smod,
    const float* __restrict__ wc, float* __restrict__ wsq,
    ushort* __restrict__ wfrag) {
  int bb = blockIdx.x;
  if (bb < 1024) {
    int wid  = (bb << 2) + (threadIdx.x >> 6);
    int lane = threadIdx.x & 63;
    int b  = wid >> 9;
    int ic = wid & 511;
    const float* s = style + b * CIN;
    const float* w = wa + (size_t)ic * CIN;
    float sum = 0.f;
#pragma unroll
    for (int k = 0; k < CIN / 64; ++k) sum += s[lane + 64 * k] * w[lane + 64 * k];
#pragma unroll
    for (int off = 32; off; off >>= 1) sum += __shfl_down(sum, off, 64);
    if (lane == 0) smod[wid] = sum * AFF_SCALE + ba[ic];
  } else if (bb < 2048) {
    int i = (bb - 1024) * 256 + threadIdx.x;
    const float* p = wc + (size_t)i * 9;
    float s = 0.f;
#pragma unroll
    for (int k = 0; k < 9; ++k) { float v = p[k]; s += v * v; }
    wsq[i] = s;
  } else {
    int n = (bb - 2048) * 256 + threadIdx.x;   // < 294,912 = 144*16*2*64
    int l    = n & 63;
    int ks   = (n >> 6) & 1;
    int mf   = (n >> 7) & 15;
    int widx = n >> 11;           // 0..143
    int g = widx / 9, p = widx % 9;
    int kh = p % 3, kw = p / 3;   // position-order storage
    int oc  = mf * 32 + (l & 31);
    int ic0 = g * 32 + ks * 16 + 8 * (l >> 5);
    s16x8 o;
#pragma unroll
    for (int j = 0; j < 8; ++j) {
      float v = wc[((size_t)oc * CIN + ic0 + j) * 9 + kh * 3 + kw];
      o[j] = (short)f2bf(v);
    }
    *(s16x8*)(wfrag + (size_t)n * 8) = o;
  }
}

// ---------------------------------------------------------------------------
// prep2: fused {demod | premod}
// ---------------------------------------------------------------------------
__global__ __launch_bounds__(256) void prep2_kernel(
    const float* __restrict__ smod, const float* __restrict__ wsq,
    float* __restrict__ demod,
    const float* __restrict__ xin, ushort* __restrict__ xt) {
  int bb = blockIdx.x;
  if (bb < 1024) {
    int wid  = (bb << 2) + (threadIdx.x >> 6);
    int lane = threadIdx.x & 63;
    int b  = wid >> 9;
    int oc = wid & 511;
    const float* s = smod + b * CIN;
    const float* w = wsq + (size_t)oc * CIN;
    float sum = 0.f;
#pragma unroll
    for (int k = 0; k < CIN / 64; ++k) {
      float sv = s[lane + 64 * k];
      sum += sv * sv * w[lane + 64 * k];
    }
#pragma unroll
    for (int off = 32; off; off >>= 1) sum += __shfl_down(sum, off, 64);
    if (lane == 0) demod[wid] = rsqrtf(sum * CONV_SCALE2 + 1e-8f) * CONV_SCALE;
  } else {
    int n = (bb - 1024) * 256 + threadIdx.x;   // < 2,097,152
    int kg = n & 3;
    int x  = (n >> 2) & 63;
    int y  = (n >> 8) & 63;
    int g  = (n >> 14) & 15;
    int b  = n >> 18;
    int ic0 = g * 32 + kg * 8;
    const float* sp = smod + b * CIN + ic0;
    const float* xp = xin + (((size_t)b * CIN + ic0) * HH + y) * WW + x;
    s16x8 o;
#pragma unroll
    for (int j = 0; j < 8; ++j) {
      float v = xp[(size_t)j * HH * WW] * sp[j];
      o[j] = (short)f2bf(v);
    }
    *(s16x8*)(xt + (size_t)n * 8) = o;
  }
}

// ---------------------------------------------------------------------------
// conv_mfma (R17): clean pre-barrier operand prefetch on R15 geometry.
// - Uniform entry barrier: vmcnt(0) lgkmcnt(0) + s_barrier (race-proof by
//   construction; all in-flight DMAs are >=1 position (~1700cyc) old, so the
//   full drain adds ~nothing).
// - wA for kstep k+1 is AREAD at the END of position k (ws[k+1] staged at
//   k-1, published by entry-of-k's drain+barrier -> unconditionally safe).
// - next-g's bA/bB pre-loaded from xs_w at end of p8 (xs_w published at p7
//   entry). Post-barrier, EVERY position starts MFMAs with zero load
//   dependency; the prefetch ds_reads drain in the pre-barrier lgkmcnt(0)
//   where wave arrival is staggered.
// Geometry/rotation/fragment maps byte-identical to R15 (verified).
// ---------------------------------------------------------------------------
#define XS_ROW 4224                 // 66 cols * 4 kg * 16 B
#define XS_BUF (6 * XS_ROW)         // 25344 B per buffer
#define WS_BUFSZ 8192               // one kstep of block weights (128oc x 32ic)

#define MFMA1(A_, B_, C_) __builtin_amdgcn_mfma_f32_32x32x16_bf16(A_, B_, C_, 0, 0, 0)

// one k-half (8 MFMAs)
#define MHK(KF, SX, SY) \
  __builtin_amdgcn_s_setprio(1); \
  acc[0][0] = MFMA1(wA[KF],     SX[0 + (KF)], acc[0][0]); \
  acc[1][0] = MFMA1(wA[2 + KF], SX[0 + (KF)], acc[1][0]); \
  acc[0][1] = MFMA1(wA[KF],     SX[2 + (KF)], acc[0][1]); \
  acc[1][1] = MFMA1(wA[2 + KF], SX[2 + (KF)], acc[1][1]); \
  acc[0][2] = MFMA1(wA[KF],     SY[0 + (KF)], acc[0][2]); \
  acc[1][2] = MFMA1(wA[2 + KF], SY[0 + (KF)], acc[1][2]); \
  acc[0][3] = MFMA1(wA[KF],     SY[2 + (KF)], acc[0][3]); \
  acc[1][3] = MFMA1(wA[2 + KF], SY[2 + (KF)], acc[1][3]); \
  __builtin_amdgcn_s_setprio(0);

// B-slot load from current read buffer
#define LOADSLOT(S, RR, DXI) \
  S[0] = *(const s16x8*)(xs_r + (wr2 + (RR)) * XS_ROW + addrV[0][DXI][0]); \
  S[1] = *(const s16x8*)(xs_r + (wr2 + (RR)) * XS_ROW + addrV[0][DXI][1]); \
  S[2] = *(const s16x8*)(xs_r + (wr2 + (RR)) * XS_ROW + addrV[1][DXI][0]); \
  S[3] = *(const s16x8*)(xs_r + (wr2 + (RR)) * XS_ROW + addrV[1][DXI][1]);

// B-slot load from the WRITE buffer (next g's tile; published at p7 entry)
#define LOADSLOTW(S, RR, DXI) \
  S[0] = *(const s16x8*)(xs_w + (wr2 + (RR)) * XS_ROW + addrV[0][DXI][0]); \
  S[1] = *(const s16x8*)(xs_w + (wr2 + (RR)) * XS_ROW + addrV[0][DXI][1]); \
  S[2] = *(const s16x8*)(xs_w + (wr2 + (RR)) * XS_ROW + addrV[1][DXI][0]); \
  S[3] = *(const s16x8*)(xs_w + (wr2 + (RR)) * XS_ROW + addrV[1][DXI][1]);

// uniform entry barrier: full drain (safe everywhere; ops are >=1 pos old)
#define ENTRYB \
  __builtin_amdgcn_sched_barrier(0); \
  asm volatile("s_waitcnt vmcnt(0) lgkmcnt(0)" ::: "memory"); \
  __builtin_amdgcn_sched_barrier(0); \
  __builtin_amdgcn_s_barrier(); \
  __builtin_amdgcn_sched_barrier(0);

// A-fragment read from ws buffer BUF (compile-time)
#define AREADB(BUF) { \
  const char* wsp_ = wsL + (BUF) * WS_BUFSZ + aoff; \
  wA[0] = *(const s16x8*)(wsp_); \
  wA[1] = *(const s16x8*)(wsp_ + 1024); \
  wA[2] = *(const s16x8*)(wsp_ + 2048); \
  wA[3] = *(const s16x8*)(wsp_ + 3072); }

// issue ws DMA for kstep (g*9 + P + 2) into buffer (P+2)%3
#define WSISSUE(P) { \
  const char* ws_s = wsg + (size_t)((P) + 2) * 32768; \
  char* ws_d = wsdst + (((P) + 2) % 3) * WS_BUFSZ; \
  gload_lds16(ws_s, ws_d); \
  gload_lds16(ws_s + 4096, ws_d + 4096); }

// normal body: each position ends with the NEXT kstep's wA prefetch
// (buffer (P+1)%3); p8 also pre-loads next g's bA/bB from xs_w.
#define GBODY(GG) \
{ \
  const char* xs_r = (const char*)lds + (GG) * XS_BUF; \
  char* xs_w = lds + ((GG) ^ 1) * XS_BUF; \
  const char* wsg = wssrcb + (size_t)(g2 * 18 + (GG) * 9) * 32768; \
  /*p0*/ ENTRYB WSISSUE(0) \
         MHK(0, bA, bB) LOADSLOT(bC, 2, 0) MHK(1, bA, bB) AREADB(1) \
  /*p1*/ ENTRYB WSISSUE(1) \
         MHK(0, bB, bC) LOADSLOT(bA, 3, 0) MHK(1, bB, bC) AREADB(2) \
  /*p2*/ ENTRYB WSISSUE(2) \
         MHK(0, bC, bA) LOADSLOT(bB, 0, 1) MHK(1, bC, bA) LOADSLOT(bC, 1, 1) AREADB(0) \
  /*p3*/ ENTRYB WSISSUE(3) \
         MHK(0, bB, bC) LOADSLOT(bA, 2, 1) MHK(1, bB, bC) AREADB(1) \
  /*p4*/ ENTRYB WSISSUE(4) \
         MHK(0, bC, bA) LOADSLOT(bB, 3, 1) MHK(1, bC, bA) AREADB(2) \
  /*p5*/ ENTRYB WSISSUE(5) \
         MHK(0, bA, bB) LOADSLOT(bC, 0, 2) MHK(1, bA, bB) LOADSLOT(bA, 1, 2) AREADB(0) \
  /*p6*/ ENTRYB WSISSUE(6) \
         stage6(xtb, (size_t)(b * 16 + g2 * 2 + (GG) + 1) * 262144, srcoff, xs_w, trash, lds_woff, y0); \
         MHK(0, bC, bA) LOADSLOT(bB, 2, 2) MHK(1, bC, bA) AREADB(1) \
  /*p7*/ ENTRYB WSISSUE(7) \
         MHK(0, bA, bB) LOADSLOT(bC, 3, 2) MHK(1, bA, bB) AREADB(2) \
  /*p8*/ ENTRYB WSISSUE(8) \
         MHK(0, bB, bC) MHK(1, bB, bC) \
         LOADSLOTW(bA, 0, 0) LOADSLOTW(bB, 1, 0) AREADB(0) \
}

// peeled last body (g=15, GG=1): no stage6; no WSISSUE(7)/(8) (past-end);
// no end-of-p8 prefetches. All entries remain full-drain (nothing to count).
#define GBODY_LAST \
{ \
  const char* xs_r = (const char*)lds + XS_BUF; \
  const char* wsg = wssrcb + (size_t)(15 * 9) * 32768; \
  /*p0*/ ENTRYB WSISSUE(0) \
         MHK(0, bA, bB) LOADSLOT(bC, 2, 0) MHK(1, bA, bB) AREADB(1) \
  /*p1*/ ENTRYB WSISSUE(1) \
         MHK(0, bB, bC) LOADSLOT(bA, 3, 0) MHK(1, bB, bC) AREADB(2) \
  /*p2*/ ENTRYB WSISSUE(2) \
         MHK(0, bC, bA) LOADSLOT(bB, 0, 1) MHK(1, bC, bA) LOADSLOT(bC, 1, 1) AREADB(0) \
  /*p3*/ ENTRYB WSISSUE(3) \
         MHK(0, bB, bC) LOADSLOT(bA, 2, 1) MHK(1, bB, bC) AREADB(1) \
  /*p4*/ ENTRYB WSISSUE(4) \
         MHK(0, bC, bA) LOADSLOT(bB, 3, 1) MHK(1, bC, bA) AREADB(2) \
  /*p5*/ ENTRYB WSISSUE(5) \
         MHK(0, bA, bB) LOADSLOT(bC, 0, 2) MHK(1, bA, bB) LOADSLOT(bA, 1, 2) AREADB(0) \
  /*p6*/ ENTRYB WSISSUE(6) \
         MHK(0, bC, bA) LOADSLOT(bB, 2, 2) MHK(1, bC, bA) AREADB(1) \
  /*p7*/ ENTRYB \
         MHK(0, bA, bB) LOADSLOT(bC, 3, 2) MHK(1, bA, bB) AREADB(2) \
  /*p8*/ ENTRYB \
         MHK(0, bB, bC) MHK(1, bB, bC) \
}

// ALWAYS issues exactly 6 DMAs (uniformity kept for simplicity; with full
// drains it is no longer load-bearing): out-of-range rows -> LDS trash row.
__device__ __forceinline__ void stage6(const char* xtb, size_t gbase, int srcoff,
                                       char* xs_w, char* trash, int lds_woff, int y0) {
  __builtin_amdgcn_sched_barrier(0);
#pragma unroll
  for (int r = 0; r < 6; ++r) {
    int gy = y0 - 1 + r;
    bool ok = (gy >= 0) && (gy < HH);
    int gyc = ok ? gy : (gy < 0 ? 0 : HH - 1);
    char* dst = ok ? (xs_w + r * XS_ROW + lds_woff) : (trash + lds_woff);
    gload_lds16(xtb + gbase + (size_t)gyc * 4096 + srcoff, dst);
  }
  __builtin_amdgcn_sched_barrier(0);
}

__global__ __launch_bounds__(256, 2) void conv_mfma(
    const ushort* __restrict__ xt,     // [8][16][64][64][32] bf16
    const ushort* __restrict__ wfrag,  // [144][16][2][64][8] bf16
    const float* __restrict__ demod,
    float* __restrict__ out) {
  // 2 xs buffers + 3 ws buffers + 1 trash row = 79488 B -> 2 blocks/CU
  __shared__ char lds[2 * XS_BUF + 3 * WS_BUFSZ + XS_ROW];

  int tid = threadIdx.x;
  int l = tid & 63, w = tid >> 6;
  int wm = w >> 1, wr = w & 1;        // oc-half, row-pair
  int wr2 = wr * 2;
  int bid = blockIdx.x;
  int ocb = bid & 3;
  int b   = (bid >> 2) & 7;
  int yt  = bid >> 5;                 // 0..15
  int y0  = yt * 4;

  const char* wsL = (const char*)lds + 2 * XS_BUF;
  char* wsdst = lds + 2 * XS_BUF + tid * 16;
  char* trash = lds + 2 * XS_BUF + 3 * WS_BUFSZ;

  f32x16 acc[2][4];
#pragma unroll
  for (int i = 0; i < 2; ++i)
#pragma unroll
    for (int j = 0; j < 4; ++j)
#pragma unroll
      for (int e = 0; e < 16; ++e) acc[i][j][e] = 0.f;

  // zero always-zero halo COLUMNS (col 0 -> chunks 0..3, col 65 -> 260..263)
  if (tid < 96) {
    int buf = tid & 1, side = (tid >> 1) & 1, kgz = (tid >> 2) & 3, r = tid >> 4;
    int chunk = side ? (260 + kgz) : kgz;
    *(int4*)(lds + buf * XS_BUF + r * XS_ROW + chunk * 16) = int4{0, 0, 0, 0};
  }
  // zero y-halo ROWS for edge blocks (never re-staged -> stay zero)
  if (y0 == 0) {
    for (int i = tid; i < 512; i += 256) {
      int buf = i & 1, chunk = 4 + (i >> 1);
      *(int4*)(lds + buf * XS_BUF + chunk * 16) = int4{0, 0, 0, 0};
    }
  }
  if (y0 == 60) {
    for (int i = tid; i < 512; i += 256) {
      int buf = i & 1, chunk = 4 + (i >> 1);
      *(int4*)(lds + buf * XS_BUF + 5 * XS_ROW + chunk * 16) = int4{0, 0, 0, 0};
    }
  }

  // B-fragment read offsets (swizzled): col = ph*32 + (l&31) + dxi,
  // kg = (l>>5) + 2*ks;  addr = (col*4 + (kg ^ ((col>>1)&3))) * 16
  int addrV[2][3][2];
  {
    int lm = l & 31, kh2 = l >> 5;
#pragma unroll
    for (int ph = 0; ph < 2; ++ph)
#pragma unroll
      for (int dxi = 0; dxi < 3; ++dxi)
#pragma unroll
        for (int ks = 0; ks < 2; ++ks) {
          int col = ph * 32 + lm + dxi;                    // 0..65
          int kg  = kh2 + 2 * ks;
          addrV[ph][dxi][ks] = (col * 4 + (kg ^ ((col >> 1) & 3))) * 16;
        }
  }

  // xs staging: wave w covers quarter w of each row; per-lane PRE-SWIZZLED
  // global source offset within a 4KB xt row (verified R5-R16)
  int col_s = 1 + w * 16 + (l >> 2);
  int srcoff = (col_s - 1) * 64 + ((l & 3) ^ ((col_s >> 1) & 3)) * 16;
  int lds_woff = 64 + w * 1024;   // + r*XS_ROW (+buf*XS_BUF)

  const char* xtb = (const char*)xt;
  // ws DMA source base: per-thread 16B chunk of the block's 8KB kstep slice
  const char* wssrcb = (const char*)wfrag + (size_t)ocb * 8192 + (size_t)tid * 16;
  // A ds_read base offset: (mf_local = wm*2+q)*2048 + ks*1024 + l*16
  int aoff = wm * 4096 + l * 16;

  // prologue: stage xs(g0), ws(k0), ws(k1); drained by __syncthreads
  {
    size_t gbase = (size_t)(b * 16) * 262144;
#pragma unroll
    for (int r = 0; r < 6; ++r) {
      int gy = y0 - 1 + r;
      if (gy >= 0 && gy < HH)
        gload_lds16(xtb + gbase + (size_t)gy * 4096 + srcoff,
                    lds + r * XS_ROW + lds_woff);
    }
    gload_lds16(wssrcb,          wsdst);
    gload_lds16(wssrcb + 4096,   wsdst + 4096);
    gload_lds16(wssrcb + 32768,        wsdst + WS_BUFSZ);
    gload_lds16(wssrcb + 32768 + 4096, wsdst + WS_BUFSZ + 4096);
  }
  __syncthreads();

  s16x8 wA[4];
  s16x8 bA[4], bB[4], bC[4];

  // one-time exposed prefetch for kstep 0 (buffer 0) + first B slots
  {
    const char* xs_r = (const char*)lds;
    AREADB(0)
    LOADSLOT(bA, 0, 0)
    LOADSLOT(bB, 1, 0)
  }

  for (int g2 = 0; g2 < 7; ++g2) {
    GBODY(0)
    GBODY(1)
  }
  {
    const int g2 = 7;
    GBODY(0)
    GBODY_LAST
  }

  // ---- epilogue: demod scale + store ----
  // C/D 32x32: col = l&31, row = (reg&3) + 8*(reg>>2) + 4*(l>>5)
  int gy_base = y0 + wr2;
  int colbase = l & 31;
  int rowadd = 4 * (l >> 5);
#pragma unroll
  for (int q = 0; q < 2; ++q) {
#pragma unroll
    for (int reg = 0; reg < 16; ++reg) {
      int row = (reg & 3) + 8 * (reg >> 2) + rowadd;
      int oc = ocb * 128 + (wm * 2 + q) * 32 + row;
      float dm = demod[b * COUT + oc];
#pragma unroll
      for (int n = 0; n < 4; ++n) {
        int gy = gy_base + (n >> 1);
        int px = (n & 1) * 32 + colbase;
        out[((size_t)(b * COUT + oc)) * 4096 + gy * 64 + px] = acc[q][n][reg] * dm;
      }
    }
  }
}

// ---------------------------------------------------------------------------
extern "C" void kernel_launch(void* const* d_in, const int* in_sizes, int n_in,
                              void* d_out, int out_size, void* d_ws, size_t ws_size,
                              hipStream_t stream) {
  const float* input = (const float*)d_in[0];  // [8,512,64,64]
  const float* style = (const float*)d_in[1];  // [8,512]
  const float* wa    = (const float*)d_in[2];  // [512,512]
  const float* ba    = (const float*)d_in[3];  // [1,512]
  const float* wconv = (const float*)d_in[4];  // [512,512,3,3]
  float* out = (float*)d_out;

  float* smod  = (float*)d_ws;                    // 4096 f
  float* demod = smod + BB * CIN;                 // 4096 f
  float* wsq   = demod + BB * COUT;               // 262144 f
  ushort* wfrag = (ushort*)(wsq + (size_t)COUT * CIN);   // 2,359,296 us (4.5 MB)
  ushort* xt    = wfrag + (size_t)16 * 9 * 32 * 64 * 8;  // 16,777,216 us (32 MB)

  prep1_kernel<<<3200, 256, 0, stream>>>(style, wa, ba, smod, wconv, wsq, wfrag);
  prep2_kernel<<<9216, 256, 0, stream>>>(smod, wsq, demod, input, xt);
  conv_mfma<<<BB * 4 * 16, 256, 0, stream>>>(xt, wfrag, demod, out);
}

// Round 18
// 146.978 us; speedup vs baseline: 2.0287x; 2.0287x over previous
//
#include <hip/hip_runtime.h>
#include <hip/hip_bf16.h>

#define BB 8
#define CIN 512
#define COUT 512
#define HH 64
#define WW 64

#define AFF_SCALE 0.044194173824159216f     // 1/sqrt(512)
#define CONV_SCALE 0.014731391274719736f    // 1/sqrt(4608)
#define CONV_SCALE2 (1.0f/4608.0f)

typedef short s16x8 __attribute__((ext_vector_type(8)));
typedef float f32x16 __attribute__((ext_vector_type(16)));

__device__ __forceinline__ unsigned short f2bf(float f) {
  __hip_bfloat16 h = __float2bfloat16(f);
  return *reinterpret_cast<unsigned short*>(&h);
}

// zero-register global->LDS DMA, 16B per lane; LDS dest = uniform base + lane*16
__device__ __forceinline__ void gload_lds16(const void* g, void* l) {
  __builtin_amdgcn_global_load_lds(
      (const __attribute__((address_space(1))) unsigned int*)g,
      (__attribute__((address_space(3))) unsigned int*)l, 16, 0, 0);
}

// ---------------------------------------------------------------------------
// prep1: fused {affine | wsq | wpack}  (independent passes, block-ranged)
// ---------------------------------------------------------------------------
__global__ __launch_bounds__(256) void prep1_kernel(
    const float* __restrict__ style, const float* __restrict__ wa,
    const float* __restrict__ ba, float* __restrict__ smod,
    const float* __restrict__ wc, float* __restrict__ wsq,
    ushort* __restrict__ wfrag) {
  int bb = blockIdx.x;
  if (bb < 1024) {
    int wid  = (bb << 2) + (threadIdx.x >> 6);
    int lane = threadIdx.x & 63;
    int b  = wid >> 9;
    int ic = wid & 511;
    const float* s = style + b * CIN;
    const float* w = wa + (size_t)ic * CIN;
    float sum = 0.f;
#pragma unroll
    for (int k = 0; k < CIN / 64; ++k) sum += s[lane + 64 * k] * w[lane + 64 * k];
#pragma unroll
    for (int off = 32; off; off >>= 1) sum += __shfl_down(sum, off, 64);
    if (lane == 0) smod[wid] = sum * AFF_SCALE + ba[ic];
  } else if (bb < 2048) {
    int i = (bb - 1024) * 256 + threadIdx.x;
    const float* p = wc + (size_t)i * 9;
    float s = 0.f;
#pragma unroll
    for (int k = 0; k < 9; ++k) { float v = p[k]; s += v * v; }
    wsq[i] = s;
  } else {
    int n = (bb - 2048) * 256 + threadIdx.x;   // < 294,912 = 144*16*2*64
    int l    = n & 63;
    int ks   = (n >> 6) & 1;
    int mf   = (n >> 7) & 15;
    int widx = n >> 11;           // 0..143
    int g = widx / 9, p = widx % 9;
    int kh = p % 3, kw = p / 3;   // position-order storage
    int oc  = mf * 32 + (l & 31);
    int ic0 = g * 32 + ks * 16 + 8 * (l >> 5);
    s16x8 o;
#pragma unroll
    for (int j = 0; j < 8; ++j) {
      float v = wc[((size_t)oc * CIN + ic0 + j) * 9 + kh * 3 + kw];
      o[j] = (short)f2bf(v);
    }
    *(s16x8*)(wfrag + (size_t)n * 8) = o;
  }
}

// ---------------------------------------------------------------------------
// prep2: fused {demod | premod}
// ---------------------------------------------------------------------------
__global__ __launch_bounds__(256) void prep2_kernel(
    const float* __restrict__ smod, const float* __restrict__ wsq,
    float* __restrict__ demod,
    const float* __restrict__ xin, ushort* __restrict__ xt) {
  int bb = blockIdx.x;
  if (bb < 1024) {
    int wid  = (bb << 2) + (threadIdx.x >> 6);
    int lane = threadIdx.x & 63;
    int b  = wid >> 9;
    int oc = wid & 511;
    const float* s = smod + b * CIN;
    const float* w = wsq + (size_t)oc * CIN;
    float sum = 0.f;
#pragma unroll
    for (int k = 0; k < CIN / 64; ++k) {
      float sv = s[lane + 64 * k];
      sum += sv * sv * w[lane + 64 * k];
    }
#pragma unroll
    for (int off = 32; off; off >>= 1) sum += __shfl_down(sum, off, 64);
    if (lane == 0) demod[wid] = rsqrtf(sum * CONV_SCALE2 + 1e-8f) * CONV_SCALE;
  } else {
    int n = (bb - 1024) * 256 + threadIdx.x;   // < 2,097,152
    int kg = n & 3;
    int x  = (n >> 2) & 63;
    int y  = (n >> 8) & 63;
    int g  = (n >> 14) & 15;
    int b  = n >> 18;
    int ic0 = g * 32 + kg * 8;
    const float* sp = smod + b * CIN + ic0;
    const float* xp = xin + (((size_t)b * CIN + ic0) * HH + y) * WW + x;
    s16x8 o;
#pragma unroll
    for (int j = 0; j < 8; ++j) {
      float v = xp[(size_t)j * HH * WW] * sp[j];
      o[j] = (short)f2bf(v);
    }
    *(s16x8*)(xt + (size_t)n * 8) = o;
  }
}

// ---------------------------------------------------------------------------
// conv_mfma (R18): R15 geometry + wA-prefetch ONLY (clean test, no spill).
// - Uniform entry barrier vmcnt(0) lgkmcnt(0) + s_barrier: race-proof by
//   construction AND makes ws[k+1] published at entry-of-k, which licenses:
// - AREADB((P+1)%3) at the END of position P (after its last wA use) ->
//   positions p1..p8 start their MFMAs post-barrier with wA already in
//   registers; the ds_read drains in the pre-barrier lgkmcnt(0).
// - NO cross-barrier B-preload (R17's spill source): p0 loads bA/bB
//   post-barrier exactly as R15 (1/9 exposure). Register tally == R15.
// ---------------------------------------------------------------------------
#define XS_ROW 4224                 // 66 cols * 4 kg * 16 B
#define XS_BUF (6 * XS_ROW)         // 25344 B per buffer
#define WS_BUFSZ 8192               // one kstep of block weights (128oc x 32ic)

#define MFMA1(A_, B_, C_) __builtin_amdgcn_mfma_f32_32x32x16_bf16(A_, B_, C_, 0, 0, 0)

// one k-half (8 MFMAs)
#define MHK(KF, SX, SY) \
  __builtin_amdgcn_s_setprio(1); \
  acc[0][0] = MFMA1(wA[KF],     SX[0 + (KF)], acc[0][0]); \
  acc[1][0] = MFMA1(wA[2 + KF], SX[0 + (KF)], acc[1][0]); \
  acc[0][1] = MFMA1(wA[KF],     SX[2 + (KF)], acc[0][1]); \
  acc[1][1] = MFMA1(wA[2 + KF], SX[2 + (KF)], acc[1][1]); \
  acc[0][2] = MFMA1(wA[KF],     SY[0 + (KF)], acc[0][2]); \
  acc[1][2] = MFMA1(wA[2 + KF], SY[0 + (KF)], acc[1][2]); \
  acc[0][3] = MFMA1(wA[KF],     SY[2 + (KF)], acc[0][3]); \
  acc[1][3] = MFMA1(wA[2 + KF], SY[2 + (KF)], acc[1][3]); \
  __builtin_amdgcn_s_setprio(0);

// B-slot load: xs row (wr2 + RR) at x-shift DXI; frags [ph*2+ks]
#define LOADSLOT(S, RR, DXI) \
  S[0] = *(const s16x8*)(xs_r + (wr2 + (RR)) * XS_ROW + addrV[0][DXI][0]); \
  S[1] = *(const s16x8*)(xs_r + (wr2 + (RR)) * XS_ROW + addrV[0][DXI][1]); \
  S[2] = *(const s16x8*)(xs_r + (wr2 + (RR)) * XS_ROW + addrV[1][DXI][0]); \
  S[3] = *(const s16x8*)(xs_r + (wr2 + (RR)) * XS_ROW + addrV[1][DXI][1]);

// uniform entry barrier: full drain (safe everywhere; in-flight ops are
// >=1 position old so the drain adds ~nothing)
#define ENTRYB \
  __builtin_amdgcn_sched_barrier(0); \
  asm volatile("s_waitcnt vmcnt(0) lgkmcnt(0)" ::: "memory"); \
  __builtin_amdgcn_sched_barrier(0); \
  __builtin_amdgcn_s_barrier(); \
  __builtin_amdgcn_sched_barrier(0);

// A-fragment read from ws buffer BUF (compile-time)
#define AREADB(BUF) { \
  const char* wsp_ = wsL + (BUF) * WS_BUFSZ + aoff; \
  wA[0] = *(const s16x8*)(wsp_); \
  wA[1] = *(const s16x8*)(wsp_ + 1024); \
  wA[2] = *(const s16x8*)(wsp_ + 2048); \
  wA[3] = *(const s16x8*)(wsp_ + 3072); }

// issue ws DMA for kstep (g*9 + P + 2) into buffer (P+2)%3
#define WSISSUE(P) { \
  const char* ws_s = wsg + (size_t)((P) + 2) * 32768; \
  char* ws_d = wsdst + (((P) + 2) % 3) * WS_BUFSZ; \
  gload_lds16(ws_s, ws_d); \
  gload_lds16(ws_s + 4096, ws_d + 4096); }

// normal body: each position ends with the NEXT kstep's wA prefetch
// (ws[k+1] is published at this position's entry drain+barrier).
#define GBODY(GG) \
{ \
  const char* xs_r = (const char*)lds + (GG) * XS_BUF; \
  char* xs_w = lds + ((GG) ^ 1) * XS_BUF; \
  const char* wsg = wssrcb + (size_t)(g2 * 18 + (GG) * 9) * 32768; \
  /*p0*/ ENTRYB \
         LOADSLOT(bA, 0, 0) LOADSLOT(bB, 1, 0) \
         WSISSUE(0) \
         MHK(0, bA, bB) LOADSLOT(bC, 2, 0) MHK(1, bA, bB) AREADB(1) \
  /*p1*/ ENTRYB WSISSUE(1) \
         MHK(0, bB, bC) LOADSLOT(bA, 3, 0) MHK(1, bB, bC) AREADB(2) \
  /*p2*/ ENTRYB WSISSUE(2) \
         MHK(0, bC, bA) LOADSLOT(bB, 0, 1) MHK(1, bC, bA) LOADSLOT(bC, 1, 1) AREADB(0) \
  /*p3*/ ENTRYB WSISSUE(3) \
         MHK(0, bB, bC) LOADSLOT(bA, 2, 1) MHK(1, bB, bC) AREADB(1) \
  /*p4*/ ENTRYB WSISSUE(4) \
         MHK(0, bC, bA) LOADSLOT(bB, 3, 1) MHK(1, bC, bA) AREADB(2) \
  /*p5*/ ENTRYB WSISSUE(5) \
         MHK(0, bA, bB) LOADSLOT(bC, 0, 2) MHK(1, bA, bB) LOADSLOT(bA, 1, 2) AREADB(0) \
  /*p6*/ ENTRYB WSISSUE(6) \
         stage6(xtb, (size_t)(b * 16 + g2 * 2 + (GG) + 1) * 262144, srcoff, xs_w, trash, lds_woff, y0); \
         MHK(0, bC, bA) LOADSLOT(bB, 2, 2) MHK(1, bC, bA) AREADB(1) \
  /*p7*/ ENTRYB WSISSUE(7) \
         MHK(0, bA, bB) LOADSLOT(bC, 3, 2) MHK(1, bA, bB) AREADB(2) \
  /*p8*/ ENTRYB WSISSUE(8) \
         MHK(0, bB, bC) MHK(1, bB, bC) AREADB(0) \
}

// peeled last body (g=15, GG=1): no stage6, no WSISSUE(7)/(8), no p8
// prefetch. End-of-p6/p7 prefetches read ws staged >=1 position earlier
// and published by the entry drains (vmcnt(0) everywhere -> always safe).
#define GBODY_LAST \
{ \
  const char* xs_r = (const char*)lds + XS_BUF; \
  const char* wsg = wssrcb + (size_t)(15 * 9) * 32768; \
  /*p0*/ ENTRYB \
         LOADSLOT(bA, 0, 0) LOADSLOT(bB, 1, 0) \
         WSISSUE(0) \
         MHK(0, bA, bB) LOADSLOT(bC, 2, 0) MHK(1, bA, bB) AREADB(1) \
  /*p1*/ ENTRYB WSISSUE(1) \
         MHK(0, bB, bC) LOADSLOT(bA, 3, 0) MHK(1, bB, bC) AREADB(2) \
  /*p2*/ ENTRYB WSISSUE(2) \
         MHK(0, bC, bA) LOADSLOT(bB, 0, 1) MHK(1, bC, bA) LOADSLOT(bC, 1, 1) AREADB(0) \
  /*p3*/ ENTRYB WSISSUE(3) \
         MHK(0, bB, bC) LOADSLOT(bA, 2, 1) MHK(1, bB, bC) AREADB(1) \
  /*p4*/ ENTRYB WSISSUE(4) \
         MHK(0, bC, bA) LOADSLOT(bB, 3, 1) MHK(1, bC, bA) AREADB(2) \
  /*p5*/ ENTRYB WSISSUE(5) \
         MHK(0, bA, bB) LOADSLOT(bC, 0, 2) MHK(1, bA, bB) LOADSLOT(bA, 1, 2) AREADB(0) \
  /*p6*/ ENTRYB WSISSUE(6) \
         MHK(0, bC, bA) LOADSLOT(bB, 2, 2) MHK(1, bC, bA) AREADB(1) \
  /*p7*/ ENTRYB \
         MHK(0, bA, bB) LOADSLOT(bC, 3, 2) MHK(1, bA, bB) AREADB(2) \
  /*p8*/ ENTRYB \
         MHK(0, bB, bC) MHK(1, bB, bC) \
}

// ALWAYS issues exactly 6 DMAs: out-of-range rows -> LDS trash row
// (uniformity kept; with full drains it is no longer load-bearing).
__device__ __forceinline__ void stage6(const char* xtb, size_t gbase, int srcoff,
                                       char* xs_w, char* trash, int lds_woff, int y0) {
  __builtin_amdgcn_sched_barrier(0);
#pragma unroll
  for (int r = 0; r < 6; ++r) {
    int gy = y0 - 1 + r;
    bool ok = (gy >= 0) && (gy < HH);
    int gyc = ok ? gy : (gy < 0 ? 0 : HH - 1);
    char* dst = ok ? (xs_w + r * XS_ROW + lds_woff) : (trash + lds_woff);
    gload_lds16(xtb + gbase + (size_t)gyc * 4096 + srcoff, dst);
  }
  __builtin_amdgcn_sched_barrier(0);
}

__global__ __launch_bounds__(256, 2) void conv_mfma(
    const ushort* __restrict__ xt,     // [8][16][64][64][32] bf16
    const ushort* __restrict__ wfrag,  // [144][16][2][64][8] bf16
    const float* __restrict__ demod,
    float* __restrict__ out) {
  // 2 xs buffers + 3 ws buffers + 1 trash row = 79488 B -> 2 blocks/CU
  __shared__ char lds[2 * XS_BUF + 3 * WS_BUFSZ + XS_ROW];

  int tid = threadIdx.x;
  int l = tid & 63, w = tid >> 6;
  int wm = w >> 1, wr = w & 1;        // oc-half, row-pair
  int wr2 = wr * 2;
  int bid = blockIdx.x;
  int ocb = bid & 3;
  int b   = (bid >> 2) & 7;
  int yt  = bid >> 5;                 // 0..15
  int y0  = yt * 4;

  const char* wsL = (const char*)lds + 2 * XS_BUF;
  char* wsdst = lds + 2 * XS_BUF + tid * 16;
  char* trash = lds + 2 * XS_BUF + 3 * WS_BUFSZ;

  f32x16 acc[2][4];
#pragma unroll
  for (int i = 0; i < 2; ++i)
#pragma unroll
    for (int j = 0; j < 4; ++j)
#pragma unroll
      for (int e = 0; e < 16; ++e) acc[i][j][e] = 0.f;

  // zero always-zero halo COLUMNS (col 0 -> chunks 0..3, col 65 -> 260..263)
  if (tid < 96) {
    int buf = tid & 1, side = (tid >> 1) & 1, kgz = (tid >> 2) & 3, r = tid >> 4;
    int chunk = side ? (260 + kgz) : kgz;
    *(int4*)(lds + buf * XS_BUF + r * XS_ROW + chunk * 16) = int4{0, 0, 0, 0};
  }
  // zero y-halo ROWS for edge blocks (never re-staged -> stay zero)
  if (y0 == 0) {
    for (int i = tid; i < 512; i += 256) {
      int buf = i & 1, chunk = 4 + (i >> 1);
      *(int4*)(lds + buf * XS_BUF + chunk * 16) = int4{0, 0, 0, 0};
    }
  }
  if (y0 == 60) {
    for (int i = tid; i < 512; i += 256) {
      int buf = i & 1, chunk = 4 + (i >> 1);
      *(int4*)(lds + buf * XS_BUF + 5 * XS_ROW + chunk * 16) = int4{0, 0, 0, 0};
    }
  }

  // B-fragment read offsets (swizzled): col = ph*32 + (l&31) + dxi,
  // kg = (l>>5) + 2*ks;  addr = (col*4 + (kg ^ ((col>>1)&3))) * 16
  int addrV[2][3][2];
  {
    int lm = l & 31, kh2 = l >> 5;
#pragma unroll
    for (int ph = 0; ph < 2; ++ph)
#pragma unroll
      for (int dxi = 0; dxi < 3; ++dxi)
#pragma unroll
        for (int ks = 0; ks < 2; ++ks) {
          int col = ph * 32 + lm + dxi;                    // 0..65
          int kg  = kh2 + 2 * ks;
          addrV[ph][dxi][ks] = (col * 4 + (kg ^ ((col >> 1) & 3))) * 16;
        }
  }

  // xs staging: wave w covers quarter w of each row; per-lane PRE-SWIZZLED
  // global source offset within a 4KB xt row (verified R5-R17)
  int col_s = 1 + w * 16 + (l >> 2);
  int srcoff = (col_s - 1) * 64 + ((l & 3) ^ ((col_s >> 1) & 3)) * 16;
  int lds_woff = 64 + w * 1024;   // + r*XS_ROW (+buf*XS_BUF)

  const char* xtb = (const char*)xt;
  // ws DMA source base: per-thread 16B chunk of the block's 8KB kstep slice
  const char* wssrcb = (const char*)wfrag + (size_t)ocb * 8192 + (size_t)tid * 16;
  // A ds_read base offset: (mf_local = wm*2+q)*2048 + ks*1024 + l*16
  int aoff = wm * 4096 + l * 16;

  // prologue: stage xs(g0), ws(k0), ws(k1); drained by __syncthreads
  {
    size_t gbase = (size_t)(b * 16) * 262144;
#pragma unroll
    for (int r = 0; r < 6; ++r) {
      int gy = y0 - 1 + r;
      if (gy >= 0 && gy < HH)
        gload_lds16(xtb + gbase + (size_t)gy * 4096 + srcoff,
                    lds + r * XS_ROW + lds_woff);
    }
    gload_lds16(wssrcb,          wsdst);
    gload_lds16(wssrcb + 4096,   wsdst + 4096);
    gload_lds16(wssrcb + 32768,        wsdst + WS_BUFSZ);
    gload_lds16(wssrcb + 32768 + 4096, wsdst + WS_BUFSZ + 4096);
  }
  __syncthreads();

  s16x8 wA[4];
  s16x8 bA[4], bB[4], bC[4];

  // one-time prefetch of kstep 0's A-fragments (ws k0 drained by syncthreads)
  AREADB(0)

  for (int g2 = 0; g2 < 7; ++g2) {
    GBODY(0)
    GBODY(1)
  }
  {
    const int g2 = 7;
    GBODY(0)
    GBODY_LAST
  }

  // ---- epilogue: demod scale + store ----
  // C/D 32x32: col = l&31, row = (reg&3) + 8*(reg>>2) + 4*(l>>5)
  int gy_base = y0 + wr2;
  int colbase = l & 31;
  int rowadd = 4 * (l >> 5);
#pragma unroll
  for (int q = 0; q < 2; ++q) {
#pragma unroll
    for (int reg = 0; reg < 16; ++reg) {
      int row = (reg & 3) + 8 * (reg >> 2) + rowadd;
      int oc = ocb * 128 + (wm * 2 + q) * 32 + row;
      float dm = demod[b * COUT + oc];
#pragma unroll
      for (int n = 0; n < 4; ++n) {
        int gy = gy_base + (n >> 1);
        int px = (n & 1) * 32 + colbase;
        out[((size_t)(b * COUT + oc)) * 4096 + gy * 64 + px] = acc[q][n][reg] * dm;
      }
    }
  }
}

// ---------------------------------------------------------------------------
extern "C" void kernel_launch(void* const* d_in, const int* in_sizes, int n_in,
                              void* d_out, int out_size, void* d_ws, size_t ws_size,
                              hipStream_t stream) {
  const float* input = (const float*)d_in[0];  // [8,512,64,64]
  const float* style = (const float*)d_in[1];  // [8,512]
  const float* wa    = (const float*)d_in[2];  // [512,512]
  const float* ba    = (const float*)d_in[3];  // [1,512]
  const float* wconv = (const float*)d_in[4];  // [512,512,3,3]
  float* out = (float*)d_out;

  float* smod  = (float*)d_ws;                    // 4096 f
  float* demod = smod + BB * CIN;                 // 4096 f
  float* wsq   = demod + BB * COUT;               // 262144 f
  ushort* wfrag = (ushort*)(wsq + (size_t)COUT * CIN);   // 2,359,296 us (4.5 MB)
  ushort* xt    = wfrag + (size_t)16 * 9 * 32 * 64 * 8;  // 16,777,216 us (32 MB)

  prep1_kernel<<<3200, 256, 0, stream>>>(style, wa, ba, smod, wconv, wsq, wfrag);
  prep2_kernel<<<9216, 256, 0, stream>>>(smod, wsq, demod, input, xt);
  conv_mfma<<<BB * 4 * 16, 256, 0, stream>>>(xt, wfrag, demod, out);
}